// Round 19
// baseline (580.729 us; speedup 1.0000x reference)
//
#include <hip/hip_runtime.h>

#define NQ 273

typedef float f4 __attribute__((ext_vector_type(4)));
typedef float f2 __attribute__((ext_vector_type(2)));

// ---------------- compile-time GA tables (Cl(3,0,1) PGA, 16 blades) ----------------
struct GATab {
  int qi[NQ]; int qj[NQ]; int qk[NQ];
  float qs[NQ];
  int qgp[NQ];
  int qpath[NQ];
  int qnew[NQ];   // 1 if this term's coef index differs from previous (after sort)
  int ngp, njp, nq;
};

constexpr int popc4(int m){ int c=0; for(int b=0;b<5;++b) c+=(m>>b)&1; return c; }
constexpr int swap_par(int a,int b){ int s=0; a>>=1; while(a){ s+=popc4(a&b); a>>=1; } return s&1; }

constexpr GATab make_tab(){
  GATab t{};
  int bladeOf[16]={}; int idxOf[16]={};
  { int p=0;
    for(int g=0; g<=4; ++g)
      for(int m=0; m<16; ++m)
        if(popc4(m)==g){ bladeOf[p]=m; idxOf[m]=p; ++p; }
  }
  int grade[16]={};
  for(int j=0;j<16;++j) grade[j]=popc4(bladeOf[j]);
  bool gpp[125]={}; bool jpp[125]={};
  for(int j=0;j<16;++j) for(int k=0;k<16;++k){
    int mj=bladeOf[j], mk=bladeOf[k];
    if(!(mj&mk&1)){ int i=idxOf[mj^mk]; gpp[(grade[i]*5+grade[j])*5+grade[k]]=true; }
    int cj=15^mj, ck=15^mk;
    if(!(cj&ck)){ int r=mj&mk; int i=idxOf[r]; jpp[(grade[i]*5+grade[j])*5+grade[k]]=true; }
  }
  int gpidx[125]={}; int jpidx[125]={};
  { int c=0; for(int u=0;u<125;++u){ gpidx[u] = gpp[u]? c++ : -1; } t.ngp=c; }
  { int c=0; for(int u=0;u<125;++u){ jpidx[u] = jpp[u]? c++ : -1; } t.njp=c; }
  int q=0;
  for(int j=0;j<16;++j) for(int k=0;k<16;++k){
    int mj=bladeOf[j], mk=bladeOf[k];
    if(!(mj&mk&1)){
      int i=idxOf[mj^mk];
      t.qi[q]=i; t.qj[q]=j; t.qk[q]=k;
      t.qs[q] = swap_par(mj,mk) ? -1.0f : 1.0f;
      t.qgp[q]=1;
      t.qpath[q]=gpidx[(grade[i]*5+grade[j])*5+grade[k]];
      ++q;
    }
  }
  for(int j=0;j<16;++j) for(int k=0;k<16;++k){
    int mj=bladeOf[j], mk=bladeOf[k];
    int cj=15^mj, ck=15^mk;
    if(!(cj&ck)){
      int r=mj&mk; int i=idxOf[r];
      int par = swap_par(mj,15^mj) ^ swap_par(mk,15^mk) ^ swap_par(cj,ck) ^ swap_par(r,15^r);
      t.qi[q]=i; t.qj[q]=j; t.qk[q]=k;
      t.qs[q] = par ? -1.0f : 1.0f;
      t.qgp[q]=0;
      t.qpath[q]=jpidx[(grade[i]*5+grade[j])*5+grade[k]];
      ++q;
    }
  }
  t.nq=q;

  // sort terms by coef index (gp paths first, then jp) so terms sharing one
  // coef value are adjacent -> ONE rolling-register LDS read per unique coef.
  for(int a=1;a<t.nq;++a){
    int ci=t.qi[a], cj2=t.qj[a], ck2=t.qk[a], cg=t.qgp[a], cp=t.qpath[a]; float cs=t.qs[a];
    int key = cg ? cp : 1000+cp;
    int b=a-1;
    while(b>=0){
      int kb = t.qgp[b] ? t.qpath[b] : 1000+t.qpath[b];
      if(kb <= key) break;
      t.qi[b+1]=t.qi[b]; t.qj[b+1]=t.qj[b]; t.qk[b+1]=t.qk[b];
      t.qs[b+1]=t.qs[b]; t.qgp[b+1]=t.qgp[b]; t.qpath[b+1]=t.qpath[b];
      --b;
    }
    t.qi[b+1]=ci; t.qj[b+1]=cj2; t.qk[b+1]=ck2; t.qs[b+1]=cs; t.qgp[b+1]=cg; t.qpath[b+1]=cp;
  }
  for(int a=0;a<t.nq;++a){
    if(a==0){ t.qnew[a]=1; continue; }
    int ka = t.qgp[a]   ? t.qpath[a]   : 1000+t.qpath[a];
    int kb = t.qgp[a-1] ? t.qpath[a-1] : 1000+t.qpath[a-1];
    t.qnew[a] = (ka!=kb) ? 1 : 0;
  }
  return t;
}

constexpr GATab TAB = make_tab();
static_assert(TAB.nq == NQ, "nonzero count mismatch");
static_assert(TAB.ngp > 0 && TAB.njp > 0, "path counts");
constexpr int NGPC = TAB.ngp;
constexpr int NJPC = TAB.njp;
constexpr int GR[16] = {0,1,1,1,1,2,2,2,2,2,2,3,3,3,3,4};

// compact coef tables: odd-padded rows -> per-lane stride odd -> 2-way bank
// aliasing only (free, m136).
constexpr int PADG = (NGPC & 1) ? NGPC : NGPC + 1;
constexpr int PADJ = (NJPC & 1) ? NJPC : NJPC + 1;
constexpr int CGF  = 64 * PADG;          // floats
constexpr int CJF  = 64 * PADJ;          // floats
constexpr int XLF  = 4 * 64 * 32;        // DUP x staging: 4 waves x 64 i x 32 dw = 32 KB
static_assert((CGF + CJF + XLF) * 4 <= 53 * 1024, "3 blocks/CU requires <=53.3KB");

// ---------------- prep kernels ----------------
// weight table fp32, PAIR-INTERLEAVED for v_pk_fma_f32:
// wrp[i][n][12] order: w1g0,w2g0,w1g1,w2g1,w1g2,w2g2,w1g3,w2g3,w1g4,w2g4,pad,pad
// -> each (w1[g],w2[g]) pair lands in adjacent VGPRs of a dwordx4 load.
__global__ void prep_wrp(const float* __restrict__ linw, float* __restrict__ wrp){
  int t = blockIdx.x*blockDim.x + threadIdx.x;
  if(t < 64*64*12){
    int s = t % 12;
    int n = (t/12) & 63;
    int i = t/(12*64);
    float v = 0.f;
    if(s < 10){
      int g = s >> 1;
      v = (s & 1) ? linw[((64+n)*64 + i)*5 + g] : linw[(n*64 + i)*5 + g];
    }
    wrp[t] = v;
  }
}

// pack gpw/jpw raw into odd-padded rows: cgj[n*PADG+p] , cgj[CGF + n*PADJ+p]
__global__ void prep_cpk(const float* __restrict__ gpw, const float* __restrict__ jpw,
                         float* __restrict__ cgj){
  int n = threadIdx.x; // blockDim = 64, grid = 1
  for(int p=0;p<NGPC;++p) cgj[n*PADG + p] = gpw[n*NGPC + p];
  for(int p=0;p<NJPC;++p) cgj[CGF + n*PADJ + p] = jpw[n*NJPC + p];
}

// ---------------- main fused kernel ----------------
// R16 skeleton + packed-fp32 linear phase (v_pk_fma_f32), zero precision risk:
//  - y12[v] = (y1[v],y2[v]) f2 accumulators (same 32 regs as before).
//  - weights fp32 pair-interleaved -> (w1[g],w2[g]) adjacent in dwordx4 dest.
//  - x staged DUPLICATED in LDS ((x,x) pairs) -> broadcast b128 reads deliver
//    ready (xv,xv) f2 operands; no dup movs, reads stay 4 b128/i.
//  - linear FMA issue halves: 32 fma/i -> 16 pk_fma/i; fp16 cvts gone.
//    VALU/element ~3300 -> ~1950 (VALU-issue was the binding pipe: R18
//    halved weight bytes for only -2% because L1 absorbs the lockstep reads).
//  - bilinear reads y12[j][0]/y12[k][1] (register halves, free); sorted
//    rolling-coef + sched_barrier(0x7) anti-hoist kept (R14).
//  - LDS 44.5 KB -> 3 blocks/CU; grid 768 = exact residency (3x256).
__global__ __launch_bounds__(256)
void main_k(const float* __restrict__ x, const float* __restrict__ cgj,
            const float* __restrict__ wrp, float* __restrict__ out, int B){
  __shared__ float lds[CGF + CJF + XLF];
  float* clg = lds;
  float* clj = lds + CGF;
  float* xl  = lds + CGF + CJF;

  const int tid  = threadIdx.x;
  const int lane = tid & 63;
  const int wv   = tid >> 6;        // 0..3
  const int n    = lane;

  // ---- stage compact coef tables once per block ----
  for(int idx = tid; idx < CGF + CJF; idx += 256) lds[idx] = cgj[idx];
  __syncthreads();

  const int cgbase = n*PADG;
  const int cjbase = n*PADJ;
  float* xw = xl + wv*2048;        // this wave's 64 i x 32 dw dup-staging region

  for(int base = blockIdx.x*4; base < B; base += gridDim.x*4){
    const int bb = base + wv;

    // ---- stage x DUPLICATED: (x0,x0,x1,x1,...) swizzled b128 writes ----
    if(bb < B){
      const f4* src = (const f4*)(x + ((long)bb*64 + lane)*16);
      #pragma unroll
      for(int r=0;r<4;++r){
        f4 a = __builtin_nontemporal_load(src+r);
        f4 d0 = __builtin_shufflevector(a, a, 0,0,1,1);
        f4 d1 = __builtin_shufflevector(a, a, 2,2,3,3);
        int base0 = lane*32 + r*8;
        *(f4*)(xw + ((base0    ) ^ ((lane&7)<<2))) = d0;
        *(f4*)(xw + ((base0 + 4) ^ ((lane&7)<<2))) = d1;
      }
    }
    // (per-wave region: in-wave lgkmcnt ordering suffices, no __syncthreads)

    // ---- linear phase (packed): y12[v] = sum_i (w1,w2)[g(v)] * (xv,xv) ----
    f2 y12[16];
    #pragma unroll
    for(int v=0;v<16;++v) y12[v] = (f2)(0.f);

    #pragma unroll 2
    for(int i=0;i<64;++i){
      const f4* wp = (const f4*)(wrp + (i*64 + n)*12);
      f4 wa = wp[0], wb = wp[1], wc = wp[2];
      f2 w12[5];
      w12[0] = __builtin_shufflevector(wa, wa, 0,1);
      w12[1] = __builtin_shufflevector(wa, wa, 2,3);
      w12[2] = __builtin_shufflevector(wb, wb, 0,1);
      w12[3] = __builtin_shufflevector(wb, wb, 2,3);
      w12[4] = __builtin_shufflevector(wc, wc, 0,1);

      // broadcast reads of dup-x: each b128 = 2 ready (xv,xv) pairs
      #pragma unroll
      for(int g=0;g<8;++g){
        int raddr = (i*32 + g*4) ^ ((i&7)<<2);
        f4 a = *(const f4*)(xw + raddr);
        f2 p0 = __builtin_shufflevector(a, a, 0,1);   // (x_{2g},   x_{2g})
        f2 p1 = __builtin_shufflevector(a, a, 2,3);   // (x_{2g+1}, x_{2g+1})
        y12[2*g]   = __builtin_elementwise_fma(w12[GR[2*g]],   p0, y12[2*g]);
        y12[2*g+1] = __builtin_elementwise_fma(w12[GR[2*g+1]], p1, y12[2*g+1]);
      }
    }

    // ---- bilinear phase: sorted terms, rolling coef register, capped hoist ----
    __builtin_amdgcn_sched_barrier(0x7);
    float acc[16];
    #pragma unroll
    for(int v=0;v<16;++v) acc[v] = y12[v][1];   // + y2

    float c = 0.f;
    #pragma unroll
    for(int q=0;q<NQ;++q){
      if(TAB.qnew[q])
        c = TAB.qgp[q] ? clg[cgbase + TAB.qpath[q]] : clj[cjbase + TAB.qpath[q]];
      float prod = y12[TAB.qj[q]][0] * y12[TAB.qk[q]][1];
      acc[TAB.qi[q]] = fmaf((TAB.qs[q] < 0.f) ? -c : c, prod, acc[TAB.qi[q]]);
      if((q % 24) == 23) __builtin_amdgcn_sched_barrier(0x7);
    }
    __builtin_amdgcn_sched_barrier(0x7);

    // ---- store (streamed once -> nontemporal) ----
    if(bb < B){
      f4* op = (f4*)(out + ((long)bb*64 + n)*16);
      #pragma unroll
      for(int r=0;r<4;++r){
        f4 o; o[0]=acc[4*r]; o[1]=acc[4*r+1]; o[2]=acc[4*r+2]; o[3]=acc[4*r+3];
        __builtin_nontemporal_store(o, op+r);
      }
    }
  }
}

extern "C" void kernel_launch(void* const* d_in, const int* in_sizes, int n_in,
                              void* d_out, int out_size, void* d_ws, size_t ws_size,
                              hipStream_t stream){
  const float* x    = (const float*)d_in[0];
  const float* gpw  = (const float*)d_in[1];
  const float* jpw  = (const float*)d_in[2];
  const float* linw = (const float*)d_in[3];
  float* outp = (float*)d_out;

  float* wrp = (float*)d_ws;           // 64*64*12 floats = 192 KB
  float* cgj = wrp + 64*64*12;         // CGF+CJF floats (~12.5 KB)

  int B = in_sizes[0] / (64*16);

  prep_wrp <<<192, 256, 0, stream>>>(linw, wrp);
  prep_cpk <<<1,   64,  0, stream>>>(gpw, jpw, cgj);
  main_k   <<<768, 256, 0, stream>>>(x, cgj, wrp, outp, B);
}

// Round 21
// 545.928 us; speedup vs baseline: 1.0637x; 1.0637x over previous
//
#include <hip/hip_runtime.h>

#define NQ 273

typedef float f4 __attribute__((ext_vector_type(4)));
typedef float f2 __attribute__((ext_vector_type(2)));

// ---------------- compile-time GA tables (Cl(3,0,1) PGA, 16 blades) ----------------
struct GATab {
  int qi[NQ]; int qj[NQ]; int qk[NQ];
  float qs[NQ];
  int qgp[NQ];
  int qpath[NQ];
  int qnew[NQ];   // 1 if this term's coef index differs from previous (after sort)
  int ngp, njp, nq;
};

constexpr int popc4(int m){ int c=0; for(int b=0;b<5;++b) c+=(m>>b)&1; return c; }
constexpr int swap_par(int a,int b){ int s=0; a>>=1; while(a){ s+=popc4(a&b); a>>=1; } return s&1; }

constexpr GATab make_tab(){
  GATab t{};
  int bladeOf[16]={}; int idxOf[16]={};
  { int p=0;
    for(int g=0; g<=4; ++g)
      for(int m=0; m<16; ++m)
        if(popc4(m)==g){ bladeOf[p]=m; idxOf[m]=p; ++p; }
  }
  int grade[16]={};
  for(int j=0;j<16;++j) grade[j]=popc4(bladeOf[j]);
  bool gpp[125]={}; bool jpp[125]={};
  for(int j=0;j<16;++j) for(int k=0;k<16;++k){
    int mj=bladeOf[j], mk=bladeOf[k];
    if(!(mj&mk&1)){ int i=idxOf[mj^mk]; gpp[(grade[i]*5+grade[j])*5+grade[k]]=true; }
    int cj=15^mj, ck=15^mk;
    if(!(cj&ck)){ int r=mj&mk; int i=idxOf[r]; jpp[(grade[i]*5+grade[j])*5+grade[k]]=true; }
  }
  int gpidx[125]={}; int jpidx[125]={};
  { int c=0; for(int u=0;u<125;++u){ gpidx[u] = gpp[u]? c++ : -1; } t.ngp=c; }
  { int c=0; for(int u=0;u<125;++u){ jpidx[u] = jpp[u]? c++ : -1; } t.njp=c; }
  int q=0;
  for(int j=0;j<16;++j) for(int k=0;k<16;++k){
    int mj=bladeOf[j], mk=bladeOf[k];
    if(!(mj&mk&1)){
      int i=idxOf[mj^mk];
      t.qi[q]=i; t.qj[q]=j; t.qk[q]=k;
      t.qs[q] = swap_par(mj,mk) ? -1.0f : 1.0f;
      t.qgp[q]=1;
      t.qpath[q]=gpidx[(grade[i]*5+grade[j])*5+grade[k]];
      ++q;
    }
  }
  for(int j=0;j<16;++j) for(int k=0;k<16;++k){
    int mj=bladeOf[j], mk=bladeOf[k];
    int cj=15^mj, ck=15^mk;
    if(!(cj&ck)){
      int r=mj&mk; int i=idxOf[r];
      int par = swap_par(mj,15^mj) ^ swap_par(mk,15^mk) ^ swap_par(cj,ck) ^ swap_par(r,15^r);
      t.qi[q]=i; t.qj[q]=j; t.qk[q]=k;
      t.qs[q] = par ? -1.0f : 1.0f;
      t.qgp[q]=0;
      t.qpath[q]=jpidx[(grade[i]*5+grade[j])*5+grade[k]];
      ++q;
    }
  }
  t.nq=q;

  // sort terms by coef index (gp paths first, then jp) so terms sharing one
  // coef value are adjacent -> ONE rolling-register LDS read per unique coef.
  for(int a=1;a<t.nq;++a){
    int ci=t.qi[a], cj2=t.qj[a], ck2=t.qk[a], cg=t.qgp[a], cp=t.qpath[a]; float cs=t.qs[a];
    int key = cg ? cp : 1000+cp;
    int b=a-1;
    while(b>=0){
      int kb = t.qgp[b] ? t.qpath[b] : 1000+t.qpath[b];
      if(kb <= key) break;
      t.qi[b+1]=t.qi[b]; t.qj[b+1]=t.qj[b]; t.qk[b+1]=t.qk[b];
      t.qs[b+1]=t.qs[b]; t.qgp[b+1]=t.qgp[b]; t.qpath[b+1]=t.qpath[b];
      --b;
    }
    t.qi[b+1]=ci; t.qj[b+1]=cj2; t.qk[b+1]=ck2; t.qs[b+1]=cs; t.qgp[b+1]=cg; t.qpath[b+1]=cp;
  }
  for(int a=0;a<t.nq;++a){
    if(a==0){ t.qnew[a]=1; continue; }
    int ka = t.qgp[a]   ? t.qpath[a]   : 1000+t.qpath[a];
    int kb = t.qgp[a-1] ? t.qpath[a-1] : 1000+t.qpath[a-1];
    t.qnew[a] = (ka!=kb) ? 1 : 0;
  }
  return t;
}

constexpr GATab TAB = make_tab();
static_assert(TAB.nq == NQ, "nonzero count mismatch");
static_assert(TAB.ngp > 0 && TAB.njp > 0, "path counts");
constexpr int NGPC = TAB.ngp;
constexpr int NJPC = TAB.njp;
constexpr int GR[16] = {0,1,1,1,1,2,2,2,2,2,2,3,3,3,3,4};

// compact coef tables: odd-padded rows -> per-lane stride odd -> 2-way bank
// aliasing only (free, m136).
constexpr int PADG = (NGPC & 1) ? NGPC : NGPC + 1;
constexpr int PADJ = (NJPC & 1) ? NJPC : NJPC + 1;
constexpr int CGF  = 64 * PADG;          // floats
constexpr int CJF  = 64 * PADJ;          // floats
constexpr int XLF  = 4 * 64 * 16;        // x staging: 4 waves x (64 i x 16 v) = 16 KB (NON-dup)
static_assert((CGF + CJF + XLF) * 4 <= 32 * 1024, "5 blocks/CU requires <=32KB");

// ---------------- prep kernels ----------------
// weight table fp32, PAIR-INTERLEAVED for v_pk_fma_f32:
// wrp[i][n][12] order: w1g0,w2g0,w1g1,w2g1,w1g2,w2g2,w1g3,w2g3,w1g4,w2g4,pad,pad
__global__ void prep_wrp(const float* __restrict__ linw, float* __restrict__ wrp){
  int t = blockIdx.x*blockDim.x + threadIdx.x;
  if(t < 64*64*12){
    int s = t % 12;
    int n = (t/12) & 63;
    int i = t/(12*64);
    float v = 0.f;
    if(s < 10){
      int g = s >> 1;
      v = (s & 1) ? linw[((64+n)*64 + i)*5 + g] : linw[(n*64 + i)*5 + g];
    }
    wrp[t] = v;
  }
}

// pack gpw/jpw raw into odd-padded rows: cgj[n*PADG+p] , cgj[CGF + n*PADJ+p]
__global__ void prep_cpk(const float* __restrict__ gpw, const float* __restrict__ jpw,
                         float* __restrict__ cgj){
  int n = threadIdx.x; // blockDim = 64, grid = 1
  for(int p=0;p<NGPC;++p) cgj[n*PADG + p] = gpw[n*NGPC + p];
  for(int p=0;p<NJPC;++p) cgj[CGF + n*PADJ + p] = jpw[n*NJPC + p];
}

// ---------------- main fused kernel ----------------
// Packed linear (R19's win: VALUBusy 65->42%) WITHOUT the dup-staging DS cost
// (R19's loss: DS instr/element 260->520, +154us stall @ ~5.5cyc/instr):
//  - x staged ONCE per element (R16 layout): 4 b128 reads + 4 writes /i-loop
//    -> DS back to ~152us/CU.
//  - splat pairs (x_c, x_c) built by shufflevector(a,a,C,C) with LITERAL
//    indices (R20 compile fix): VOP3P op_sel can express same-word-both-
//    halves, so ISel folds the splat into the v_pk_fma_f32 operand.
//    Fallback risk bounded: if not folded -> 16 movs/i ~ R18-neutral.
//  - weights fp32 pair-interleaved (R19 prep): (w1[g],w2[g]) adjacent regs.
//  - y12[v]=(y1,y2) packed accumulators; bilinear reads register halves.
//  - sorted rolling-coef + sched_barrier(0x7) anti-hoist (R14).
//  - LDS 28.5 KB -> 5 blocks/CU; grid 1280 = exact residency (5x256).
__global__ __launch_bounds__(256)
void main_k(const float* __restrict__ x, const float* __restrict__ cgj,
            const float* __restrict__ wrp, float* __restrict__ out, int B){
  __shared__ float lds[CGF + CJF + XLF];
  float* clg = lds;
  float* clj = lds + CGF;
  float* xl  = lds + CGF + CJF;

  const int tid  = threadIdx.x;
  const int lane = tid & 63;
  const int wv   = tid >> 6;        // 0..3
  const int n    = lane;

  // ---- stage compact coef tables once per block ----
  for(int idx = tid; idx < CGF + CJF; idx += 256) lds[idx] = cgj[idx];
  __syncthreads();

  const int cgbase = n*PADG;
  const int cjbase = n*PADJ;
  float* xw = xl + wv*1024;        // this wave's 64 i x 16 v staging region

  for(int base = blockIdx.x*4; base < B; base += gridDim.x*4){
    const int bb = base + wv;

    // ---- stage x: lane writes its channel row (swizzled b128, bank-floor) ----
    if(bb < B){
      const f4* src = (const f4*)(x + ((long)bb*64 + lane)*16);
      #pragma unroll
      for(int r=0;r<4;++r){
        f4 a = __builtin_nontemporal_load(src+r);
        int daddr = (lane*16 + r*4) ^ ((lane&7)<<2);
        *(f4*)(xw + daddr) = a;
      }
    }
    // (per-wave region: in-wave lgkmcnt ordering suffices, no __syncthreads)

    // ---- linear phase (packed): y12[v] = sum_i (w1,w2)[g(v)] * (xv,xv) ----
    f2 y12[16];
    #pragma unroll
    for(int v=0;v<16;++v) y12[v] = (f2)(0.f);

    #pragma unroll 2
    for(int i=0;i<64;++i){
      const f4* wp = (const f4*)(wrp + (i*64 + n)*12);
      f4 wa = wp[0], wb = wp[1], wc = wp[2];
      f2 w12[5];
      w12[0] = __builtin_shufflevector(wa, wa, 0,1);
      w12[1] = __builtin_shufflevector(wa, wa, 2,3);
      w12[2] = __builtin_shufflevector(wb, wb, 0,1);
      w12[3] = __builtin_shufflevector(wb, wb, 2,3);
      w12[4] = __builtin_shufflevector(wc, wc, 0,1);

      // broadcast reads of x (uniform addr, conflict-free); splats (x_c,x_c)
      // with literal lane indices -> foldable into op_sel of v_pk_fma_f32
      #pragma unroll
      for(int g=0;g<4;++g){
        int raddr = (i*16 + g*4) ^ ((i&7)<<2);
        f4 a = *(const f4*)(xw + raddr);
        f2 p0 = __builtin_shufflevector(a, a, 0,0);
        f2 p1 = __builtin_shufflevector(a, a, 1,1);
        f2 p2 = __builtin_shufflevector(a, a, 2,2);
        f2 p3 = __builtin_shufflevector(a, a, 3,3);
        y12[g*4+0] = __builtin_elementwise_fma(w12[GR[g*4+0]], p0, y12[g*4+0]);
        y12[g*4+1] = __builtin_elementwise_fma(w12[GR[g*4+1]], p1, y12[g*4+1]);
        y12[g*4+2] = __builtin_elementwise_fma(w12[GR[g*4+2]], p2, y12[g*4+2]);
        y12[g*4+3] = __builtin_elementwise_fma(w12[GR[g*4+3]], p3, y12[g*4+3]);
      }
    }

    // ---- bilinear phase: sorted terms, rolling coef register, capped hoist ----
    __builtin_amdgcn_sched_barrier(0x7);
    float acc[16];
    #pragma unroll
    for(int v=0;v<16;++v) acc[v] = y12[v][1];   // + y2

    float c = 0.f;
    #pragma unroll
    for(int q=0;q<NQ;++q){
      if(TAB.qnew[q])
        c = TAB.qgp[q] ? clg[cgbase + TAB.qpath[q]] : clj[cjbase + TAB.qpath[q]];
      float prod = y12[TAB.qj[q]][0] * y12[TAB.qk[q]][1];
      acc[TAB.qi[q]] = fmaf((TAB.qs[q] < 0.f) ? -c : c, prod, acc[TAB.qi[q]]);
      if((q % 24) == 23) __builtin_amdgcn_sched_barrier(0x7);
    }
    __builtin_amdgcn_sched_barrier(0x7);

    // ---- store (streamed once -> nontemporal) ----
    if(bb < B){
      f4* op = (f4*)(out + ((long)bb*64 + n)*16);
      #pragma unroll
      for(int r=0;r<4;++r){
        f4 o; o[0]=acc[4*r]; o[1]=acc[4*r+1]; o[2]=acc[4*r+2]; o[3]=acc[4*r+3];
        __builtin_nontemporal_store(o, op+r);
      }
    }
  }
}

extern "C" void kernel_launch(void* const* d_in, const int* in_sizes, int n_in,
                              void* d_out, int out_size, void* d_ws, size_t ws_size,
                              hipStream_t stream){
  const float* x    = (const float*)d_in[0];
  const float* gpw  = (const float*)d_in[1];
  const float* jpw  = (const float*)d_in[2];
  const float* linw = (const float*)d_in[3];
  float* outp = (float*)d_out;

  float* wrp = (float*)d_ws;           // 64*64*12 floats = 192 KB
  float* cgj = wrp + 64*64*12;         // CGF+CJF floats (~12.5 KB)

  int B = in_sizes[0] / (64*16);

  prep_wrp <<<192, 256, 0, stream>>>(linw, wrp);
  prep_cpk <<<1,   64,  0, stream>>>(gpw, jpw, cgj);
  main_k   <<<1280, 256, 0, stream>>>(x, cgj, wrp, outp, B);
}

// Round 23
// 480.967 us; speedup vs baseline: 1.2074x; 1.1351x over previous
//
#include <hip/hip_runtime.h>

#define NQ 273

typedef float f4 __attribute__((ext_vector_type(4)));
typedef float f2 __attribute__((ext_vector_type(2)));
typedef _Float16 hf2 __attribute__((ext_vector_type(2)));

// ---------------- compile-time GA tables (Cl(3,0,1) PGA, 16 blades) ----------------
struct GATab {
  int qi[NQ]; int qj[NQ]; int qk[NQ];
  float qs[NQ];
  int qgp[NQ];
  int qpath[NQ];
  int qnew[NQ];   // 1 if this term's coef index differs from previous (after sort)
  int ngp, njp, nq;
};

constexpr int popc4(int m){ int c=0; for(int b=0;b<5;++b) c+=(m>>b)&1; return c; }
constexpr int swap_par(int a,int b){ int s=0; a>>=1; while(a){ s+=popc4(a&b); a>>=1; } return s&1; }

constexpr GATab make_tab(){
  GATab t{};
  int bladeOf[16]={}; int idxOf[16]={};
  { int p=0;
    for(int g=0; g<=4; ++g)
      for(int m=0; m<16; ++m)
        if(popc4(m)==g){ bladeOf[p]=m; idxOf[m]=p; ++p; }
  }
  int grade[16]={};
  for(int j=0;j<16;++j) grade[j]=popc4(bladeOf[j]);
  bool gpp[125]={}; bool jpp[125]={};
  for(int j=0;j<16;++j) for(int k=0;k<16;++k){
    int mj=bladeOf[j], mk=bladeOf[k];
    if(!(mj&mk&1)){ int i=idxOf[mj^mk]; gpp[(grade[i]*5+grade[j])*5+grade[k]]=true; }
    int cj=15^mj, ck=15^mk;
    if(!(cj&ck)){ int r=mj&mk; int i=idxOf[r]; jpp[(grade[i]*5+grade[j])*5+grade[k]]=true; }
  }
  int gpidx[125]={}; int jpidx[125]={};
  { int c=0; for(int u=0;u<125;++u){ gpidx[u] = gpp[u]? c++ : -1; } t.ngp=c; }
  { int c=0; for(int u=0;u<125;++u){ jpidx[u] = jpp[u]? c++ : -1; } t.njp=c; }
  int q=0;
  for(int j=0;j<16;++j) for(int k=0;k<16;++k){
    int mj=bladeOf[j], mk=bladeOf[k];
    if(!(mj&mk&1)){
      int i=idxOf[mj^mk];
      t.qi[q]=i; t.qj[q]=j; t.qk[q]=k;
      t.qs[q] = swap_par(mj,mk) ? -1.0f : 1.0f;
      t.qgp[q]=1;
      t.qpath[q]=gpidx[(grade[i]*5+grade[j])*5+grade[k]];
      ++q;
    }
  }
  for(int j=0;j<16;++j) for(int k=0;k<16;++k){
    int mj=bladeOf[j], mk=bladeOf[k];
    int cj=15^mj, ck=15^mk;
    if(!(cj&ck)){
      int r=mj&mk; int i=idxOf[r];
      int par = swap_par(mj,15^mj) ^ swap_par(mk,15^mk) ^ swap_par(cj,ck) ^ swap_par(r,15^r);
      t.qi[q]=i; t.qj[q]=j; t.qk[q]=k;
      t.qs[q] = par ? -1.0f : 1.0f;
      t.qgp[q]=0;
      t.qpath[q]=jpidx[(grade[i]*5+grade[j])*5+grade[k]];
      ++q;
    }
  }
  t.nq=q;

  // sort terms by coef index (gp paths first, then jp) so terms sharing one
  // coef value are adjacent -> ONE rolling-register LDS read per unique coef.
  for(int a=1;a<t.nq;++a){
    int ci=t.qi[a], cj2=t.qj[a], ck2=t.qk[a], cg=t.qgp[a], cp=t.qpath[a]; float cs=t.qs[a];
    int key = cg ? cp : 1000+cp;
    int b=a-1;
    while(b>=0){
      int kb = t.qgp[b] ? t.qpath[b] : 1000+t.qpath[b];
      if(kb <= key) break;
      t.qi[b+1]=t.qi[b]; t.qj[b+1]=t.qj[b]; t.qk[b+1]=t.qk[b];
      t.qs[b+1]=t.qs[b]; t.qgp[b+1]=t.qgp[b]; t.qpath[b+1]=t.qpath[b];
      --b;
    }
    t.qi[b+1]=ci; t.qj[b+1]=cj2; t.qk[b+1]=ck2; t.qs[b+1]=cs; t.qgp[b+1]=cg; t.qpath[b+1]=cp;
  }
  for(int a=0;a<t.nq;++a){
    if(a==0){ t.qnew[a]=1; continue; }
    int ka = t.qgp[a]   ? t.qpath[a]   : 1000+t.qpath[a];
    int kb = t.qgp[a-1] ? t.qpath[a-1] : 1000+t.qpath[a-1];
    t.qnew[a] = (ka!=kb) ? 1 : 0;
  }
  return t;
}

constexpr GATab TAB = make_tab();
static_assert(TAB.nq == NQ, "nonzero count mismatch");
static_assert(TAB.ngp > 0 && TAB.njp > 0, "path counts");
constexpr int NGPC = TAB.ngp;
constexpr int NJPC = TAB.njp;
constexpr int GR[16] = {0,1,1,1,1,2,2,2,2,2,2,3,3,3,3,4};

// compact coef tables (fp32 in LDS, R21-proven): odd-padded rows -> per-lane
// stride odd -> 2-way bank aliasing only (free, m136).
constexpr int PADG = (NGPC & 1) ? NGPC : NGPC + 1;
constexpr int PADJ = (NJPC & 1) ? NJPC : NJPC + 1;
constexpr int CGF  = 64 * PADG;          // floats
constexpr int CJF  = 64 * PADJ;          // floats
constexpr int XLF  = 4 * 64 * 16;        // x staging: 4 waves x (64 i x 16 v) = 16 KB
static_assert((CGF + CJF + XLF) * 4 <= 32 * 1024, "5 blocks/CU requires <=32KB");

// ---------------- prep kernels ----------------
// R18-proven fp16 weight table: wrph[(i*5+s)*64 + n] = h(w1[g=s]) | h(w2[g=s])<<16
// 20 B/lane/i instead of 48 -> L1 weight re-read per element 192 -> 80 KB
// (the hypothesized binding pipe: R14/R18/R21 all pinned at 545 while VALU
// varied 250-394us). Each u32 IS the (w1,w2) pair -> unpacks directly into
// the packed v_pk_fma_f32 operand.
__global__ void prep_wrph(const float* __restrict__ linw, unsigned* __restrict__ wrph){
  int t = blockIdx.x*blockDim.x + threadIdx.x;
  if(t < 64*5*64){
    int n = t & 63;
    int s = (t >> 6) % 5;
    int i = t / 320;
    float w1 = linw[(n*64 + i)*5 + s];
    float w2 = linw[((64+n)*64 + i)*5 + s];
    unsigned short a = __builtin_bit_cast(unsigned short, (_Float16)w1);
    unsigned short b = __builtin_bit_cast(unsigned short, (_Float16)w2);
    wrph[t] = (unsigned)a | ((unsigned)b << 16);
  }
}

// pack gpw/jpw raw (fp32) into odd-padded rows: cgj[n*PADG+p] , cgj[CGF + n*PADJ+p]
__global__ void prep_cpk(const float* __restrict__ gpw, const float* __restrict__ jpw,
                         float* __restrict__ cgj){
  int n = threadIdx.x; // blockDim = 64, grid = 1
  for(int p=0;p<NGPC;++p) cgj[n*PADG + p] = gpw[n*NGPC + p];
  for(int p=0;p<NJPC;++p) cgj[CGF + n*PADJ + p] = jpw[n*NJPC + p];
}

// ---------------- main fused kernel ----------------
// R21 skeleton (packed-fp32 linear, PASSED 545us) + R18's fp16 weight table
// (PASSED, absmax 0.125). ONE effective change vs R21: weight bytes 48->20
// per lane/i -> clean test of the L1-weight-stream hypothesis.
// (R22 bundled 3 untested layout changes and broke correctness; reverted.)
//  - x staged once per element, swizzled b128 writes, wave-uniform broadcast
//    f4 reads (0 conflicts); splats (x_c,x_c) via literal shufflevector ->
//    fold into VOP3P op_sel.
//  - y12[v]=(y1,y2) packed accumulators; 16 pk_fma/i.
//  - coef fp32 in LDS, sorted rolling-coef + sched_barrier(0x7) (R14).
//  - LDS 28.5 KB -> 5 blocks/CU; grid 1280 = exact residency.
__global__ __launch_bounds__(256)
void main_k(const float* __restrict__ x, const float* __restrict__ cgj,
            const unsigned* __restrict__ wrph, float* __restrict__ out, int B){
  __shared__ float lds[CGF + CJF + XLF];
  float* clg = lds;
  float* clj = lds + CGF;
  float* xl  = lds + CGF + CJF;

  const int tid  = threadIdx.x;
  const int lane = tid & 63;
  const int wv   = tid >> 6;        // 0..3
  const int n    = lane;

  // ---- stage coef tables once per block ----
  for(int idx = tid; idx < CGF + CJF; idx += 256) lds[idx] = cgj[idx];
  __syncthreads();

  const int cgbase = n*PADG;
  const int cjbase = n*PADJ;
  float* xw = xl + wv*1024;        // this wave's 64 i x 16 v staging region

  for(int base = blockIdx.x*4; base < B; base += gridDim.x*4){
    const int bb = base + wv;

    // ---- stage x: lane writes its channel row (swizzled b128, bank-floor) ----
    if(bb < B){
      const f4* src = (const f4*)(x + ((long)bb*64 + lane)*16);
      #pragma unroll
      for(int r=0;r<4;++r){
        f4 a = __builtin_nontemporal_load(src+r);
        int daddr = (lane*16 + r*4) ^ ((lane&7)<<2);
        *(f4*)(xw + daddr) = a;
      }
    }
    // (per-wave region: in-wave lgkmcnt ordering suffices, no __syncthreads)

    // ---- linear phase (packed): y12[v] = sum_i (w1,w2)[g(v)] * (xv,xv) ----
    f2 y12[16];
    #pragma unroll
    for(int v=0;v<16;++v) y12[v] = (f2)(0.f);

    #pragma unroll 2
    for(int i=0;i<64;++i){
      const unsigned* wp = wrph + i*320 + n;
      unsigned u0 = wp[0], u1 = wp[64], u2 = wp[128], u3 = wp[192], u4 = wp[256];
      f2 w12[5];
      { hf2 h = __builtin_bit_cast(hf2, u0); w12[0][0]=(float)h[0]; w12[0][1]=(float)h[1]; }
      { hf2 h = __builtin_bit_cast(hf2, u1); w12[1][0]=(float)h[0]; w12[1][1]=(float)h[1]; }
      { hf2 h = __builtin_bit_cast(hf2, u2); w12[2][0]=(float)h[0]; w12[2][1]=(float)h[1]; }
      { hf2 h = __builtin_bit_cast(hf2, u3); w12[3][0]=(float)h[0]; w12[3][1]=(float)h[1]; }
      { hf2 h = __builtin_bit_cast(hf2, u4); w12[4][0]=(float)h[0]; w12[4][1]=(float)h[1]; }

      // broadcast reads of x (uniform addr, conflict-free); splats (x_c,x_c)
      // with literal lane indices -> foldable into op_sel of v_pk_fma_f32
      #pragma unroll
      for(int g=0;g<4;++g){
        int raddr = (i*16 + g*4) ^ ((i&7)<<2);
        f4 a = *(const f4*)(xw + raddr);
        f2 p0 = __builtin_shufflevector(a, a, 0,0);
        f2 p1 = __builtin_shufflevector(a, a, 1,1);
        f2 p2 = __builtin_shufflevector(a, a, 2,2);
        f2 p3 = __builtin_shufflevector(a, a, 3,3);
        y12[g*4+0] = __builtin_elementwise_fma(w12[GR[g*4+0]], p0, y12[g*4+0]);
        y12[g*4+1] = __builtin_elementwise_fma(w12[GR[g*4+1]], p1, y12[g*4+1]);
        y12[g*4+2] = __builtin_elementwise_fma(w12[GR[g*4+2]], p2, y12[g*4+2]);
        y12[g*4+3] = __builtin_elementwise_fma(w12[GR[g*4+3]], p3, y12[g*4+3]);
      }
    }

    // ---- bilinear phase: sorted terms, rolling coef register, capped hoist ----
    __builtin_amdgcn_sched_barrier(0x7);
    float acc[16];
    #pragma unroll
    for(int v=0;v<16;++v) acc[v] = y12[v][1];   // + y2

    float c = 0.f;
    #pragma unroll
    for(int q=0;q<NQ;++q){
      if(TAB.qnew[q])
        c = TAB.qgp[q] ? clg[cgbase + TAB.qpath[q]] : clj[cjbase + TAB.qpath[q]];
      float prod = y12[TAB.qj[q]][0] * y12[TAB.qk[q]][1];
      acc[TAB.qi[q]] = fmaf((TAB.qs[q] < 0.f) ? -c : c, prod, acc[TAB.qi[q]]);
      if((q % 24) == 23) __builtin_amdgcn_sched_barrier(0x7);
    }
    __builtin_amdgcn_sched_barrier(0x7);

    // ---- store (streamed once -> nontemporal) ----
    if(bb < B){
      f4* op = (f4*)(out + ((long)bb*64 + n)*16);
      #pragma unroll
      for(int r=0;r<4;++r){
        f4 o; o[0]=acc[4*r]; o[1]=acc[4*r+1]; o[2]=acc[4*r+2]; o[3]=acc[4*r+3];
        __builtin_nontemporal_store(o, op+r);
      }
    }
  }
}

extern "C" void kernel_launch(void* const* d_in, const int* in_sizes, int n_in,
                              void* d_out, int out_size, void* d_ws, size_t ws_size,
                              hipStream_t stream){
  const float* x    = (const float*)d_in[0];
  const float* gpw  = (const float*)d_in[1];
  const float* jpw  = (const float*)d_in[2];
  const float* linw = (const float*)d_in[3];
  float* outp = (float*)d_out;

  unsigned* wrph = (unsigned*)d_ws;            // 64*5*64 u32 = 80 KB
  float*    cgj  = (float*)(wrph + 64*5*64);   // CGF+CJF floats (~12.5 KB)

  int B = in_sizes[0] / (64*16);

  prep_wrph<<<80, 256, 0, stream>>>(linw, wrph);
  prep_cpk <<<1,  64,  0, stream>>>(gpw, jpw, cgj);
  main_k   <<<1280, 256, 0, stream>>>(x, cgj, wrph, outp, B);
}

// Round 24
// 476.943 us; speedup vs baseline: 1.2176x; 1.0084x over previous
//
#include <hip/hip_runtime.h>

#define NQ 273

typedef float f4 __attribute__((ext_vector_type(4)));
typedef float f2 __attribute__((ext_vector_type(2)));
typedef _Float16 hf2 __attribute__((ext_vector_type(2)));

// ---------------- compile-time GA tables (Cl(3,0,1) PGA, 16 blades) ----------------
struct GATab {
  int qi[NQ]; int qj[NQ]; int qk[NQ];
  float qs[NQ];
  int qgp[NQ];
  int qpath[NQ];
  int qnew[NQ];   // 1 if this term's coef index differs from previous (after sort)
  int ngp, njp, nq;
};

constexpr int popc4(int m){ int c=0; for(int b=0;b<5;++b) c+=(m>>b)&1; return c; }
constexpr int swap_par(int a,int b){ int s=0; a>>=1; while(a){ s+=popc4(a&b); a>>=1; } return s&1; }

constexpr GATab make_tab(){
  GATab t{};
  int bladeOf[16]={}; int idxOf[16]={};
  { int p=0;
    for(int g=0; g<=4; ++g)
      for(int m=0; m<16; ++m)
        if(popc4(m)==g){ bladeOf[p]=m; idxOf[m]=p; ++p; }
  }
  int grade[16]={};
  for(int j=0;j<16;++j) grade[j]=popc4(bladeOf[j]);
  bool gpp[125]={}; bool jpp[125]={};
  for(int j=0;j<16;++j) for(int k=0;k<16;++k){
    int mj=bladeOf[j], mk=bladeOf[k];
    if(!(mj&mk&1)){ int i=idxOf[mj^mk]; gpp[(grade[i]*5+grade[j])*5+grade[k]]=true; }
    int cj=15^mj, ck=15^mk;
    if(!(cj&ck)){ int r=mj&mk; int i=idxOf[r]; jpp[(grade[i]*5+grade[j])*5+grade[k]]=true; }
  }
  int gpidx[125]={}; int jpidx[125]={};
  { int c=0; for(int u=0;u<125;++u){ gpidx[u] = gpp[u]? c++ : -1; } t.ngp=c; }
  { int c=0; for(int u=0;u<125;++u){ jpidx[u] = jpp[u]? c++ : -1; } t.njp=c; }
  int q=0;
  for(int j=0;j<16;++j) for(int k=0;k<16;++k){
    int mj=bladeOf[j], mk=bladeOf[k];
    if(!(mj&mk&1)){
      int i=idxOf[mj^mk];
      t.qi[q]=i; t.qj[q]=j; t.qk[q]=k;
      t.qs[q] = swap_par(mj,mk) ? -1.0f : 1.0f;
      t.qgp[q]=1;
      t.qpath[q]=gpidx[(grade[i]*5+grade[j])*5+grade[k]];
      ++q;
    }
  }
  for(int j=0;j<16;++j) for(int k=0;k<16;++k){
    int mj=bladeOf[j], mk=bladeOf[k];
    int cj=15^mj, ck=15^mk;
    if(!(cj&ck)){
      int r=mj&mk; int i=idxOf[r];
      int par = swap_par(mj,15^mj) ^ swap_par(mk,15^mk) ^ swap_par(cj,ck) ^ swap_par(r,15^r);
      t.qi[q]=i; t.qj[q]=j; t.qk[q]=k;
      t.qs[q] = par ? -1.0f : 1.0f;
      t.qgp[q]=0;
      t.qpath[q]=jpidx[(grade[i]*5+grade[j])*5+grade[k]];
      ++q;
    }
  }
  t.nq=q;

  // sort terms by coef index (gp paths first, then jp) so terms sharing one
  // coef value are adjacent -> ONE rolling-register LDS read per unique coef.
  for(int a=1;a<t.nq;++a){
    int ci=t.qi[a], cj2=t.qj[a], ck2=t.qk[a], cg=t.qgp[a], cp=t.qpath[a]; float cs=t.qs[a];
    int key = cg ? cp : 1000+cp;
    int b=a-1;
    while(b>=0){
      int kb = t.qgp[b] ? t.qpath[b] : 1000+t.qpath[b];
      if(kb <= key) break;
      t.qi[b+1]=t.qi[b]; t.qj[b+1]=t.qj[b]; t.qk[b+1]=t.qk[b];
      t.qs[b+1]=t.qs[b]; t.qgp[b+1]=t.qgp[b]; t.qpath[b+1]=t.qpath[b];
      --b;
    }
    t.qi[b+1]=ci; t.qj[b+1]=cj2; t.qk[b+1]=ck2; t.qs[b+1]=cs; t.qgp[b+1]=cg; t.qpath[b+1]=cp;
  }
  for(int a=0;a<t.nq;++a){
    if(a==0){ t.qnew[a]=1; continue; }
    int ka = t.qgp[a]   ? t.qpath[a]   : 1000+t.qpath[a];
    int kb = t.qgp[a-1] ? t.qpath[a-1] : 1000+t.qpath[a-1];
    t.qnew[a] = (ka!=kb) ? 1 : 0;
  }
  return t;
}

constexpr GATab TAB = make_tab();
static_assert(TAB.nq == NQ, "nonzero count mismatch");
static_assert(TAB.ngp > 0 && TAB.njp > 0, "path counts");
constexpr int NGPC = TAB.ngp;
constexpr int NJPC = TAB.njp;
constexpr int GR[16] = {0,1,1,1,1,2,2,2,2,2,2,3,3,3,3,4};

// compact coef tables (fp32 in LDS, proven): odd-padded rows -> per-lane
// stride odd -> 2-way bank aliasing only (free, m136).
constexpr int PADG = (NGPC & 1) ? NGPC : NGPC + 1;
constexpr int PADJ = (NJPC & 1) ? NJPC : NJPC + 1;
constexpr int CGF  = 64 * PADG;          // floats
constexpr int CJF  = 64 * PADJ;          // floats
constexpr int XLF  = 4 * 64 * 16;        // x staging: 4 waves x (64 i x 16 v) = 16 KB
static_assert((CGF + CJF + XLF) * 4 <= 32 * 1024, "5 blocks/CU requires <=32KB");

// ---------------- prep kernels ----------------
// fp16 weight table (R18/R23-proven): wrph[(i*5+s)*64+n] = h(w1[s]) | h(w2[s])<<16
__global__ void prep_wrph(const float* __restrict__ linw, unsigned* __restrict__ wrph){
  int t = blockIdx.x*blockDim.x + threadIdx.x;
  if(t < 64*5*64){
    int n = t & 63;
    int s = (t >> 6) % 5;
    int i = t / 320;
    float w1 = linw[(n*64 + i)*5 + s];
    float w2 = linw[((64+n)*64 + i)*5 + s];
    unsigned short a = __builtin_bit_cast(unsigned short, (_Float16)w1);
    unsigned short b = __builtin_bit_cast(unsigned short, (_Float16)w2);
    wrph[t] = (unsigned)a | ((unsigned)b << 16);
  }
}

// pack gpw/jpw raw (fp32) into odd-padded rows
__global__ void prep_cpk(const float* __restrict__ gpw, const float* __restrict__ jpw,
                         float* __restrict__ cgj){
  int n = threadIdx.x; // blockDim = 64, grid = 1
  for(int p=0;p<NGPC;++p) cgj[n*PADG + p] = gpw[n*NGPC + p];
  for(int p=0;p<NJPC;++p) cgj[CGF + n*PADJ + p] = jpw[n*NJPC + p];
}

// ---------------- main fused kernel ----------------
// R23 (PASSED 481us) + latency pipelining. R23 accounting: VALU/DS/L1 each
// ~130-175us/CU yet dur ~500 -> latency-bound (pipes idle while each wave
// serially waits). Two fixes, both "issue loads one stage early":
//  1. x PREFETCH ROTATION: issue next element's 4 nontemporal loads at pass
//     start (into regs); linear phase (~6k cyc) covers the ~900cyc HBM
//     latency; write regs -> SAME per-wave LDS buffer after the linear reads
//     complete (no extra LDS, no sync needed). Removes the full x round-trip
//     from the pass critical path.
//  2. i-loop unroll 2 -> 4: wider scheduler window for the weight-load
//     stream (cross-iteration L1 latency ~120cyc x 32 steps otherwise).
// Everything else frozen from R23: packed-fp32 linear via fp16 pair weights,
// coef fp32 in LDS + sorted rolling-coef + sched_barrier(0x7), swizzled
// b128 staging / broadcast reads, 5 blocks/CU, grid 1280.
__global__ __launch_bounds__(256)
void main_k(const float* __restrict__ x, const float* __restrict__ cgj,
            const unsigned* __restrict__ wrph, float* __restrict__ out, int B){
  __shared__ float lds[CGF + CJF + XLF];
  float* clg = lds;
  float* clj = lds + CGF;
  float* xl  = lds + CGF + CJF;

  const int tid  = threadIdx.x;
  const int lane = tid & 63;
  const int wv   = tid >> 6;        // 0..3
  const int n    = lane;

  // ---- stage coef tables once per block ----
  for(int idx = tid; idx < CGF + CJF; idx += 256) lds[idx] = cgj[idx];
  __syncthreads();

  const int cgbase = n*PADG;
  const int cjbase = n*PADJ;
  float* xw = xl + wv*1024;        // this wave's 64 i x 16 v staging region
  const int stride = gridDim.x*4;

  // ---- prologue: load + stage first element ----
  int bb = blockIdx.x*4 + wv;
  if(bb < B){
    const f4* src = (const f4*)(x + ((long)bb*64 + lane)*16);
    #pragma unroll
    for(int r=0;r<4;++r){
      f4 a = __builtin_nontemporal_load(src+r);
      int daddr = (lane*16 + r*4) ^ ((lane&7)<<2);
      *(f4*)(xw + daddr) = a;
    }
  }

  for(; bb < B; bb += stride){
    const int nb = bb + stride;

    // ---- issue NEXT element's loads now (HBM latency hides under linear) ----
    f4 xn[4];
    if(nb < B){
      const f4* src = (const f4*)(x + ((long)nb*64 + lane)*16);
      #pragma unroll
      for(int r=0;r<4;++r) xn[r] = __builtin_nontemporal_load(src+r);
    }

    // ---- linear phase (packed): y12[v] = sum_i (w1,w2)[g(v)] * (xv,xv) ----
    f2 y12[16];
    #pragma unroll
    for(int v=0;v<16;++v) y12[v] = (f2)(0.f);

    #pragma unroll 4
    for(int i=0;i<64;++i){
      const unsigned* wp = wrph + i*320 + n;
      unsigned u0 = wp[0], u1 = wp[64], u2 = wp[128], u3 = wp[192], u4 = wp[256];
      f2 w12[5];
      { hf2 h = __builtin_bit_cast(hf2, u0); w12[0][0]=(float)h[0]; w12[0][1]=(float)h[1]; }
      { hf2 h = __builtin_bit_cast(hf2, u1); w12[1][0]=(float)h[0]; w12[1][1]=(float)h[1]; }
      { hf2 h = __builtin_bit_cast(hf2, u2); w12[2][0]=(float)h[0]; w12[2][1]=(float)h[1]; }
      { hf2 h = __builtin_bit_cast(hf2, u3); w12[3][0]=(float)h[0]; w12[3][1]=(float)h[1]; }
      { hf2 h = __builtin_bit_cast(hf2, u4); w12[4][0]=(float)h[0]; w12[4][1]=(float)h[1]; }

      // broadcast reads of x (uniform addr, conflict-free); splats (x_c,x_c)
      // with literal lane indices -> fold into VOP3P op_sel
      #pragma unroll
      for(int g=0;g<4;++g){
        int raddr = (i*16 + g*4) ^ ((i&7)<<2);
        f4 a = *(const f4*)(xw + raddr);
        f2 p0 = __builtin_shufflevector(a, a, 0,0);
        f2 p1 = __builtin_shufflevector(a, a, 1,1);
        f2 p2 = __builtin_shufflevector(a, a, 2,2);
        f2 p3 = __builtin_shufflevector(a, a, 3,3);
        y12[g*4+0] = __builtin_elementwise_fma(w12[GR[g*4+0]], p0, y12[g*4+0]);
        y12[g*4+1] = __builtin_elementwise_fma(w12[GR[g*4+1]], p1, y12[g*4+1]);
        y12[g*4+2] = __builtin_elementwise_fma(w12[GR[g*4+2]], p2, y12[g*4+2]);
        y12[g*4+3] = __builtin_elementwise_fma(w12[GR[g*4+3]], p3, y12[g*4+3]);
      }
    }

    // ---- stage NEXT element into the (now fully-read) buffer ----
    if(nb < B){
      #pragma unroll
      for(int r=0;r<4;++r){
        int daddr = (lane*16 + r*4) ^ ((lane&7)<<2);
        *(f4*)(xw + daddr) = xn[r];
      }
    }

    // ---- bilinear phase: sorted terms, rolling coef register, capped hoist ----
    __builtin_amdgcn_sched_barrier(0x7);
    float acc[16];
    #pragma unroll
    for(int v=0;v<16;++v) acc[v] = y12[v][1];   // + y2

    float c = 0.f;
    #pragma unroll
    for(int q=0;q<NQ;++q){
      if(TAB.qnew[q])
        c = TAB.qgp[q] ? clg[cgbase + TAB.qpath[q]] : clj[cjbase + TAB.qpath[q]];
      float prod = y12[TAB.qj[q]][0] * y12[TAB.qk[q]][1];
      acc[TAB.qi[q]] = fmaf((TAB.qs[q] < 0.f) ? -c : c, prod, acc[TAB.qi[q]]);
      if((q % 24) == 23) __builtin_amdgcn_sched_barrier(0x7);
    }
    __builtin_amdgcn_sched_barrier(0x7);

    // ---- store (streamed once -> nontemporal) ----
    {
      f4* op = (f4*)(out + ((long)bb*64 + n)*16);
      #pragma unroll
      for(int r=0;r<4;++r){
        f4 o; o[0]=acc[4*r]; o[1]=acc[4*r+1]; o[2]=acc[4*r+2]; o[3]=acc[4*r+3];
        __builtin_nontemporal_store(o, op+r);
      }
    }
  }
}

extern "C" void kernel_launch(void* const* d_in, const int* in_sizes, int n_in,
                              void* d_out, int out_size, void* d_ws, size_t ws_size,
                              hipStream_t stream){
  const float* x    = (const float*)d_in[0];
  const float* gpw  = (const float*)d_in[1];
  const float* jpw  = (const float*)d_in[2];
  const float* linw = (const float*)d_in[3];
  float* outp = (float*)d_out;

  unsigned* wrph = (unsigned*)d_ws;            // 64*5*64 u32 = 80 KB
  float*    cgj  = (float*)(wrph + 64*5*64);   // CGF+CJF floats (~12.5 KB)

  int B = in_sizes[0] / (64*16);

  prep_wrph<<<80, 256, 0, stream>>>(linw, wrph);
  prep_cpk <<<1,  64,  0, stream>>>(gpw, jpw, cgj);
  main_k   <<<1280, 256, 0, stream>>>(x, cgj, wrph, outp, B);
}